// Round 4
// baseline (227.380 us; speedup 1.0000x reference)
//
#include <hip/hip_runtime.h>

// Sparsemax over last dim, rows of N=512 fp32.
// One 64-lane wave per TWO rows (ILP=2 on every dependent chain);
// 8 elements/lane/row in registers.
// tau via Newton (== Michelot) on f(tau)=sum(max(z-tau,0))-1, started at
// tau0 = rowmax - 1 (provably <= tau*, support ~5-8 elems on Gaussian data
// -> ~3-4 iterations instead of ~10 from the full-support start).
// Reductions: DPP chains (pure VALU); counts via ballot + scalar popcount.

#define ROW_N 512
#define LANES 64
#define EPL 8  // elements per lane per row

#define DPP_ADD_STEP(v, ctrl, rmask)                                        \
  v += __int_as_float(__builtin_amdgcn_update_dpp(                          \
      0, __float_as_int(v), ctrl, rmask, 0xf, true))

#define DPP_MAX_STEP(v, ctrl, rmask)                                        \
  v = fmaxf(v, __int_as_float(__builtin_amdgcn_update_dpp(                  \
             __float_as_int(v), __float_as_int(v), ctrl, rmask, 0xf, false)))

// Two independent 64-lane sums, chains interleaved so each hides the
// other's dependent-op latency.
__device__ inline void wave_sum64_x2(float& u, float& v) {
  DPP_ADD_STEP(u, 0x111, 0xf); DPP_ADD_STEP(v, 0x111, 0xf);  // row_shr:1
  DPP_ADD_STEP(u, 0x112, 0xf); DPP_ADD_STEP(v, 0x112, 0xf);  // row_shr:2
  DPP_ADD_STEP(u, 0x114, 0xf); DPP_ADD_STEP(v, 0x114, 0xf);  // row_shr:4
  DPP_ADD_STEP(u, 0x118, 0xf); DPP_ADD_STEP(v, 0x118, 0xf);  // row_shr:8
  DPP_ADD_STEP(u, 0x142, 0xa); DPP_ADD_STEP(v, 0x142, 0xa);  // row_bcast:15
  DPP_ADD_STEP(u, 0x143, 0xc); DPP_ADD_STEP(v, 0x143, 0xc);  // row_bcast:31
  u = __int_as_float(__builtin_amdgcn_readlane(__float_as_int(u), 63));
  v = __int_as_float(__builtin_amdgcn_readlane(__float_as_int(v), 63));
}

__device__ inline void wave_max64_x2(float& u, float& v) {
  DPP_MAX_STEP(u, 0x111, 0xf); DPP_MAX_STEP(v, 0x111, 0xf);
  DPP_MAX_STEP(u, 0x112, 0xf); DPP_MAX_STEP(v, 0x112, 0xf);
  DPP_MAX_STEP(u, 0x114, 0xf); DPP_MAX_STEP(v, 0x114, 0xf);
  DPP_MAX_STEP(u, 0x118, 0xf); DPP_MAX_STEP(v, 0x118, 0xf);
  DPP_MAX_STEP(u, 0x142, 0xa); DPP_MAX_STEP(v, 0x142, 0xa);
  DPP_MAX_STEP(u, 0x143, 0xc); DPP_MAX_STEP(v, 0x143, 0xc);
  u = __int_as_float(__builtin_amdgcn_readlane(__float_as_int(u), 63));
  v = __int_as_float(__builtin_amdgcn_readlane(__float_as_int(v), 63));
}

__global__ __launch_bounds__(256) void sparsemax_kernel(
    const float* __restrict__ x, float* __restrict__ out, int nrows) {
  const int lane = threadIdx.x & 63;
  const int wid = blockIdx.x * 4 + (threadIdx.x >> 6);
  const int row0 = wid * 2;
  if (row0 >= nrows) return;
  const int row1 = (row0 + 1 < nrows) ? row0 + 1 : row0;

  const float4* xr0 = (const float4*)(x + (size_t)row0 * ROW_N);
  const float4* xr1 = (const float4*)(x + (size_t)row1 * ROW_N);
  float4 a0 = xr0[lane], b0 = xr0[lane + LANES];
  float4 a1 = xr1[lane], b1 = xr1[lane + LANES];
  float z0[EPL] = {a0.x, a0.y, a0.z, a0.w, b0.x, b0.y, b0.z, b0.w};
  float z1[EPL] = {a1.x, a1.y, a1.z, a1.w, b1.x, b1.y, b1.z, b1.w};

  // Per-lane tree max (depth 3), then interleaved wave max.
  float m0 = fmaxf(fmaxf(fmaxf(z0[0], z0[1]), fmaxf(z0[2], z0[3])),
                   fmaxf(fmaxf(z0[4], z0[5]), fmaxf(z0[6], z0[7])));
  float m1 = fmaxf(fmaxf(fmaxf(z1[0], z1[1]), fmaxf(z1[2], z1[3])),
                   fmaxf(fmaxf(z1[4], z1[5]), fmaxf(z1[6], z1[7])));
  wave_max64_x2(m0, m1);

  // tau* in [m-1, m): at tau=m-1 the max element alone contributes 1 to
  // sum(max(z-tau,0)), so f(m-1) >= 0. Newton from the left is monotone.
  float tau0 = m0 - 1.0f, tau1 = m1 - 1.0f;
  int prev0 = -1, prev1 = -1;
  for (int iter = 0; iter < 16; ++iter) {
    float t0[EPL], t1[EPL];
    int k0 = 0, k1 = 0;
#pragma unroll
    for (int i = 0; i < EPL; ++i) {
      bool g0 = z0[i] > tau0;
      bool g1 = z1[i] > tau1;
      t0[i] = g0 ? z0[i] : 0.0f;  // same v_cmp mask feeds cndmask AND ballot
      t1[i] = g1 ? z1[i] : 0.0f;
      k0 += (int)__popcll(__ballot(g0));  // scalar pipe
      k1 += (int)__popcll(__ballot(g1));
    }
    float ls0 = ((t0[0] + t0[1]) + (t0[2] + t0[3])) +
                ((t0[4] + t0[5]) + (t0[6] + t0[7]));
    float ls1 = ((t1[0] + t1[1]) + (t1[2] + t1[3])) +
                ((t1[4] + t1[5]) + (t1[6] + t1[7]));
    wave_sum64_x2(ls0, ls1);
    tau0 = (ls0 - 1.0f) * __builtin_amdgcn_rcpf((float)k0);
    tau1 = (ls1 - 1.0f) * __builtin_amdgcn_rcpf((float)k1);
    // Support sets shrink monotonically; equal counts => equal sets =>
    // both taus are fixed points. Iterating a converged row is a no-op.
    if (k0 == prev0 && k1 == prev1) break;
    prev0 = k0; prev1 = k1;
  }

  float4 oa0 = {fmaxf(z0[0] - tau0, 0.0f), fmaxf(z0[1] - tau0, 0.0f),
                fmaxf(z0[2] - tau0, 0.0f), fmaxf(z0[3] - tau0, 0.0f)};
  float4 ob0 = {fmaxf(z0[4] - tau0, 0.0f), fmaxf(z0[5] - tau0, 0.0f),
                fmaxf(z0[6] - tau0, 0.0f), fmaxf(z0[7] - tau0, 0.0f)};
  float4 oa1 = {fmaxf(z1[0] - tau1, 0.0f), fmaxf(z1[1] - tau1, 0.0f),
                fmaxf(z1[2] - tau1, 0.0f), fmaxf(z1[3] - tau1, 0.0f)};
  float4 ob1 = {fmaxf(z1[4] - tau1, 0.0f), fmaxf(z1[5] - tau1, 0.0f),
                fmaxf(z1[6] - tau1, 0.0f), fmaxf(z1[7] - tau1, 0.0f)};
  float4* or0 = (float4*)(out + (size_t)row0 * ROW_N);
  float4* or1 = (float4*)(out + (size_t)row1 * ROW_N);
  or0[lane] = oa0;
  or0[lane + LANES] = ob0;
  or1[lane] = oa1;
  or1[lane + LANES] = ob1;
}

extern "C" void kernel_launch(void* const* d_in, const int* in_sizes, int n_in,
                              void* d_out, int out_size, void* d_ws,
                              size_t ws_size, hipStream_t stream) {
  const float* x = (const float*)d_in[0];
  float* out = (float*)d_out;
  const int nrows = in_sizes[0] / ROW_N;
  const int blocks = (nrows + 7) / 8;  // 4 waves/block x 2 rows/wave
  sparsemax_kernel<<<blocks, 256, 0, stream>>>(x, out, nrows);
}